// Round 5
// baseline (206.095 us; speedup 1.0000x reference)
//
#include <hip/hip_runtime.h>

#define NB 8
#define NS 2048
#define ND 512
#define QB 64
#define KB 512
#define NKT (NS / KB)   // 4

// LDS offsets (bytes); Qs/Ps XOR-swizzled (T2), no padding
#define QS_OFF   0         // 64*512*2 = 65536
#define PS_OFF   65536     // 64*512*2 = 65536
#define TMAX_OFF 131072    // 64*12*4  = 3072
#define TSUM_OFF 134144    // 3072
#define MROW_OFF 137216    // 2*64*4   = 512
#define AROW_OFF 137728    // 256
#define LROW_OFF 137984    // 256
#define LDS_BYTES 138240

typedef __attribute__((ext_vector_type(4)))  float f32x4;
typedef __attribute__((ext_vector_type(16))) float f32x16;
typedef __attribute__((ext_vector_type(8)))  short s16x8;

__device__ __forceinline__ unsigned short f2bf(float f) {
    unsigned int u = __float_as_uint(f);
    u += 0x7FFF + ((u >> 16) & 1);
    return (unsigned short)(u >> 16);
}

// ---- pre-pass: Q,K fp32 -> bf16 (Q pre-scaled by 1/sqrt(D)) ----
__global__ void cvt_qk_kernel(const float* __restrict__ Q, const float* __restrict__ K,
                              unsigned short* __restrict__ Qb, unsigned short* __restrict__ Kb) {
    const float scale = 0.04419417382415922f;
    size_t i = ((size_t)blockIdx.x * 256 + threadIdx.x) * 4;
    float4 q = *(const float4*)(Q + i);
    float4 k = *(const float4*)(K + i);
    ushort4 qo, ko;
    qo.x = f2bf(q.x * scale); qo.y = f2bf(q.y * scale);
    qo.z = f2bf(q.z * scale); qo.w = f2bf(q.w * scale);
    ko.x = f2bf(k.x); ko.y = f2bf(k.y); ko.z = f2bf(k.z); ko.w = f2bf(k.w);
    *(ushort4*)(Qb + i) = qo;
    *(ushort4*)(Kb + i) = ko;
}

// ---- pre-pass: V fp32 [b][s][d] -> V^T bf16 [b][d][s] ----
__global__ void cvt_vt_kernel(const float* __restrict__ V, unsigned short* __restrict__ Vt) {
    __shared__ float tile[32][33];
    int bid = blockIdx.x;
    int dt = bid & 15;
    int st = (bid >> 4) & 63;
    int b  = bid >> 10;
    int t = threadIdx.x;
    int sl = t >> 3, dq = t & 7;
    const float* src = V + ((size_t)b * NS + st * 32 + sl) * ND + dt * 32 + dq * 4;
    float4 v = *(const float4*)src;
    tile[sl][dq * 4 + 0] = v.x; tile[sl][dq * 4 + 1] = v.y;
    tile[sl][dq * 4 + 2] = v.z; tile[sl][dq * 4 + 3] = v.w;
    __syncthreads();
    int dl = t >> 3, sq = t & 7;
    ushort4 o;
    o.x = f2bf(tile[sq * 4 + 0][dl]);
    o.y = f2bf(tile[sq * 4 + 1][dl]);
    o.z = f2bf(tile[sq * 4 + 2][dl]);
    o.w = f2bf(tile[sq * 4 + 3][dl]);
    *(ushort4*)(Vt + ((size_t)b * ND + dt * 32 + dl) * NS + st * 32 + sq * 4) = o;
}

// ---- main flash-attention kernel ----
// grid 256; 512 threads (8 waves); b = blockIdx&7 (XCD affinity: batch's K+V = 4MB = one L2).
// KB=512 split as 2 sub-tiles of 256; QK^T swapped (A=K,B=Q) in 32x32x16:
// wave w owns k-rows {sub*256 + w*32 ..+32}; each Q fragment read feeds 4 MFMAs.
// PV in 16x16x32: wave w owns output d-cols [w*64, w*64+64).
__global__ void __launch_bounds__(512, 2) attn_kernel(const unsigned short* __restrict__ Qg_,
                                                      const unsigned short* __restrict__ Kg_,
                                                      const unsigned short* __restrict__ Vg_,
                                                      float* __restrict__ out) {
    extern __shared__ __align__(16) char smem[];
    unsigned short* Qs = (unsigned short*)(smem + QS_OFF);   // [64][512] swizzled
    unsigned short* Ps = (unsigned short*)(smem + PS_OFF);   // [64][512] swizzled
    float* tmax = (float*)(smem + TMAX_OFF);                 // [64][12]
    float* tsum = (float*)(smem + TSUM_OFF);                 // [64][12]
    float* mrow = (float*)(smem + MROW_OFF);                 // [2][64]
    float* arow = (float*)(smem + AROW_OFF);                 // [64]
    float* lrow = (float*)(smem + LROW_OFF);                 // [64]

    const int tid  = threadIdx.x;
    const int lane = tid & 63;
    const int w    = tid >> 6;     // 0..7
    const int hi   = lane >> 5;    // 0/1
    const int l31  = lane & 31;
    const int g    = lane >> 4;    // 0..3 (PV)
    const int c    = lane & 15;    // 0..15 (PV)
    const int b    = blockIdx.x & 7;
    const int qt   = blockIdx.x >> 3;

    const unsigned short* Qg = Qg_ + ((size_t)b * NS + qt * QB) * ND;
    const unsigned short* Kg = Kg_ + (size_t)b * NS * ND;
    const unsigned short* Vg = Vg_ + (size_t)b * ND * NS;   // [512][2048]

    // stage Q tile (64 x 512), swizzled: col ^= (row&7)<<3 (shorts)
    #pragma unroll
    for (int it = 0; it < 8; ++it) {
        int idx = it * 4096 + tid * 8;
        int r = idx >> 9, cc = idx & 511;
        *(s16x8*)(Qs + r * 512 + (cc ^ ((r & 7) << 3))) = *(const s16x8*)(Qg + idx);
    }
    if (tid < 64) { mrow[tid] = -INFINITY; lrow[tid] = 0.f; }
    __syncthreads();

    f32x4 o[4][4];
    #pragma unroll
    for (int i = 0; i < 4; ++i)
        for (int j = 0; j < 4; ++j) o[i][j] = (f32x4){0.f, 0.f, 0.f, 0.f};

    // K A-frag base: row = sub*256 + w*32 + l31, d-slice offset hi*8
    const unsigned short* Kp = Kg + (size_t)(w * 32 + l31) * ND + hi * 8;
    // V B-frag base: d-row = w*64 + c, k-offset g*8
    const unsigned short* Vp = Vg + (size_t)(w * 64 + c) * NS + g * 8;
    const int qsw = (l31 & 7) << 3;

    // 4-deep K fragment rings, one per k-sub-tile
    s16x8 kr0[4], kr1[4];
    #pragma unroll
    for (int p = 0; p < 4; ++p) {
        kr0[p] = *(const s16x8*)(Kp + p * 16);
        kr1[p] = *(const s16x8*)(Kp + (size_t)256 * ND + p * 16);
    }

    for (int kt = 0; kt < NKT; ++kt) {
        const size_t kts = (size_t)kt * KB;
        const unsigned short* K0 = Kp + kts * ND;                 // sub0 rows
        const unsigned short* K1 = Kp + (kts + 256) * ND;         // sub1 rows
        const unsigned short* Kn0 = Kp + (kts + KB) * ND;         // next kt sub0
        const unsigned short* Kn1 = Kp + (kts + KB + 256) * ND;   // next kt sub1

        // ---- QK^T: sc[qb][sub] = S[k = sub*256 + w*32 + rowmap][q = qb*32 + l31] ----
        f32x16 sc[2][2];
        sc[0][0] = (f32x16)0.f; sc[0][1] = (f32x16)0.f;
        sc[1][0] = (f32x16)0.f; sc[1][1] = (f32x16)0.f;
        #pragma unroll
        for (int s = 0; s < 32; ++s) {
            const int rg = s & 3;
            s16x8 qf0 = *(const s16x8*)(Qs + (l31)      * 512 + ((s * 16 + hi * 8) ^ qsw));
            s16x8 qf1 = *(const s16x8*)(Qs + (32 + l31) * 512 + ((s * 16 + hi * 8) ^ qsw));
            __builtin_amdgcn_s_setprio(1);
            sc[0][0] = __builtin_amdgcn_mfma_f32_32x32x16_bf16(kr0[rg], qf0, sc[0][0], 0, 0, 0);
            sc[1][0] = __builtin_amdgcn_mfma_f32_32x32x16_bf16(kr0[rg], qf1, sc[1][0], 0, 0, 0);
            sc[0][1] = __builtin_amdgcn_mfma_f32_32x32x16_bf16(kr1[rg], qf0, sc[0][1], 0, 0, 0);
            sc[1][1] = __builtin_amdgcn_mfma_f32_32x32x16_bf16(kr1[rg], qf1, sc[1][1], 0, 0, 0);
            __builtin_amdgcn_s_setprio(0);
            if (s < 28) {
                kr0[rg] = *(const s16x8*)(K0 + (s + 4) * 16);
                kr1[rg] = *(const s16x8*)(K1 + (s + 4) * 16);
            } else if (kt < NKT - 1) {
                kr0[rg] = *(const s16x8*)(Kn0 + (s - 28) * 16);
                kr1[rg] = *(const s16x8*)(Kn1 + (s - 28) * 16);
            }
        }

        // issue V for ks=0..3 early (hide latency under softmax)
        s16x8 bv[4][4];
        #pragma unroll
        for (int ks = 0; ks < 4; ++ks)
            #pragma unroll
            for (int nb = 0; nb < 4; ++nb)
                bv[ks][nb] = *(const s16x8*)(Vp + (size_t)nb * 16 * NS + kts + ks * 32);

        // ---- wave-local per-q max over wave's 64 k (2 subs x 16 regs) ----
        #pragma unroll
        for (int qb = 0; qb < 2; ++qb) {
            float m0 = sc[qb][0][0];
            #pragma unroll
            for (int r = 1; r < 16; ++r) m0 = fmaxf(m0, sc[qb][0][r]);
            #pragma unroll
            for (int r = 0; r < 16; ++r) m0 = fmaxf(m0, sc[qb][1][r]);
            m0 = fmaxf(m0, __shfl_xor(m0, 32));
            if (lane < 32) tmax[(qb * 32 + l31) * 12 + w] = m0;
        }
        __syncthreads();                                     // B1
        const int par = kt & 1;
        {   // cooperative max/alpha (8 dup writers per row, same value)
            int row = tid & 63;
            f32x4 t0 = *(const f32x4*)(tmax + row * 12);
            f32x4 t1 = *(const f32x4*)(tmax + row * 12 + 4);
            float mx = fmaxf(fmaxf(fmaxf(t0[0], t0[1]), fmaxf(t0[2], t0[3])),
                             fmaxf(fmaxf(t1[0], t1[1]), fmaxf(t1[2], t1[3])));
            float mo = mrow[par * 64 + row];
            float mn = fmaxf(mo, mx);
            mrow[(par ^ 1) * 64 + row] = mn;
            arow[row] = __expf(mo - mn);
        }
        __syncthreads();                                     // B2

        // ---- P = exp(S-m), row sums, P -> LDS packed+swizzled ----
        #pragma unroll
        for (int qb = 0; qb < 2; ++qb) {
            const int q = qb * 32 + l31;
            float mq = mrow[(par ^ 1) * 64 + q];
            #pragma unroll
            for (int sub = 0; sub < 2; ++sub)
                #pragma unroll
                for (int r = 0; r < 16; ++r) sc[qb][sub][r] = __expf(sc[qb][sub][r] - mq);
            float s0 = 0.f;
            #pragma unroll
            for (int r = 0; r < 16; ++r) s0 += sc[qb][0][r] + sc[qb][1][r];
            s0 += __shfl_xor(s0, 32);
            if (lane < 32) tsum[q * 12 + w] = s0;
            const int psw = (q & 7) << 3;
            #pragma unroll
            for (int sub = 0; sub < 2; ++sub)
                #pragma unroll
                for (int rg = 0; rg < 4; ++rg) {   // k = sub*256 + w*32 + rg*8 + hi*4 + 0..3
                    ushort4 pk;
                    pk.x = f2bf(sc[qb][sub][rg * 4 + 0]); pk.y = f2bf(sc[qb][sub][rg * 4 + 1]);
                    pk.z = f2bf(sc[qb][sub][rg * 4 + 2]); pk.w = f2bf(sc[qb][sub][rg * 4 + 3]);
                    *(ushort4*)(Ps + q * 512 + ((sub * 256 + w * 32 + rg * 8 + hi * 4) ^ psw)) = pk;
                }
        }
        // rescale O by alpha
        #pragma unroll
        for (int qb = 0; qb < 4; ++qb)
            #pragma unroll
            for (int r = 0; r < 4; ++r) {
                float al = arow[qb * 16 + g * 4 + r];
                #pragma unroll
                for (int nb = 0; nb < 4; ++nb) o[qb][nb][r] *= al;
            }
        __syncthreads();                                     // B3
        if (tid < 64) {
            int row = tid;
            f32x4 s0 = *(const f32x4*)(tsum + row * 12);
            f32x4 s1 = *(const f32x4*)(tsum + row * 12 + 4);
            float ls = (s0[0] + s0[1] + s0[2] + s0[3]) + (s1[0] + s1[1] + s1[2] + s1[3]);
            lrow[row] = lrow[row] * arow[row] + ls;
        }

        // ---- PV: O[64 x 64(w)] += P(64x512) @ V(512x64) ----
        #pragma unroll
        for (int ks = 0; ks < 16; ++ks) {
            const int sl = ks & 3;
            s16x8 ap[4];
            #pragma unroll
            for (int qb = 0; qb < 4; ++qb) {
                const int q = qb * 16 + c;
                ap[qb] = *(const s16x8*)(Ps + q * 512 + ((ks * 32 + g * 8) ^ ((q & 7) << 3)));
            }
            __builtin_amdgcn_s_setprio(1);
            #pragma unroll
            for (int qb = 0; qb < 4; ++qb)
                #pragma unroll
                for (int nb = 0; nb < 4; ++nb)
                    o[qb][nb] = __builtin_amdgcn_mfma_f32_16x16x32_bf16(ap[qb], bv[sl][nb], o[qb][nb], 0, 0, 0);
            __builtin_amdgcn_s_setprio(0);
            if (ks < 12)
                #pragma unroll
                for (int nb = 0; nb < 4; ++nb)
                    bv[sl][nb] = *(const s16x8*)(Vp + (size_t)nb * 16 * NS + kts + (ks + 4) * 32);
        }
    }

    __syncthreads();
    float* Og = out + ((size_t)b * NS + qt * QB) * ND;
    #pragma unroll
    for (int qb = 0; qb < 4; ++qb)
        #pragma unroll
        for (int r = 0; r < 4; ++r) {
            float li = 1.f / lrow[qb * 16 + g * 4 + r];
            #pragma unroll
            for (int nb = 0; nb < 4; ++nb)
                Og[(size_t)(qb * 16 + g * 4 + r) * ND + w * 64 + nb * 16 + c] =
                    o[qb][nb][r] * li;
        }
}

extern "C" void kernel_launch(void* const* d_in, const int* in_sizes, int n_in,
                              void* d_out, int out_size, void* d_ws, size_t ws_size,
                              hipStream_t stream) {
    const float* V = (const float*)d_in[0];
    const float* K = (const float*)d_in[1];
    const float* Q = (const float*)d_in[2];
    float* out = (float*)d_out;

    unsigned short* Qb = (unsigned short*)d_ws;
    unsigned short* Kb = Qb + (size_t)NB * NS * ND;
    unsigned short* Vt = Kb + (size_t)NB * NS * ND;

    hipFuncSetAttribute(reinterpret_cast<const void*>(attn_kernel),
                        hipFuncAttributeMaxDynamicSharedMemorySize, LDS_BYTES);

    cvt_qk_kernel<<<8192, 256, 0, stream>>>(Q, K, Qb, Kb);
    cvt_vt_kernel<<<8192, 256, 0, stream>>>(V, Vt);
    attn_kernel<<<NB * (NS / QB), 512, LDS_BYTES, stream>>>(Qb, Kb, Vt, out);
}